// Round 9
// baseline (43.982 us; speedup 1.0000x reference)
//
#include <hip/hip_runtime.h>
#include <hip/hip_bf16.h>

// Problem constants
#define BB 32
#define GG 1024
#define VV 10000
#define KHID 1024
#define MM 128
#define NCHUNK 625      // 625 * 16 = 10000 rows exactly
#define GEMM_GRID 256

typedef __attribute__((ext_vector_type(8))) short short8;
typedef __attribute__((ext_vector_type(4))) float f32x4;

// f32 -> bf16 bits, round-to-nearest-even (scalar; used in convW)
__device__ __forceinline__ unsigned short bf16_rne(float f) {
    union { float f; unsigned int u; } v; v.f = f;
    unsigned int r = v.u + 0x7FFFu + ((v.u >> 16) & 1u);
    return (unsigned short)(r >> 16);
}

// pack 2 f32 -> 1 u32 of 2 bf16 (RNE); compiler emits v_cvt_pk_bf16_f32
__device__ __forceinline__ unsigned int pk2(float lo, float hi) {
    __hip_bfloat162 h = __float22bfloat162_rn(make_float2(lo, hi));
    union { __hip_bfloat162 h; unsigned int u; } cv; cv.h = h;
    return cv.u;
}

// bf16 bits -> f32
__device__ __forceinline__ float bfu(unsigned short u) {
    union { unsigned int u; float f; } v; v.u = (unsigned int)u << 16;
    return v.f;
}

// LDS-only barrier: waits LDS ops then raw s_barrier; does NOT drain vmcnt,
// so global prefetch loads stay in flight across it.
__device__ __forceinline__ void lds_barrier() {
    asm volatile("s_waitcnt lgkmcnt(0)" ::: "memory");
    __builtin_amdgcn_s_barrier();
    asm volatile("" ::: "memory");
}

// ---------------------------------------------------------------------------
// K0: WtB[col][k] = bf16(W_fc[HID + k][col])  (transpose+convert, LDS-tiled)
// ---------------------------------------------------------------------------
__global__ __launch_bounds__(256) void k_convW(const float* __restrict__ Wfc,
                                               unsigned short* __restrict__ WtB) {
    __shared__ float Lt[64][33];
    const int k0 = blockIdx.x * 64, c0 = blockIdx.y * 32;
    const int tid = threadIdx.x;
    const float* Wg = Wfc + (size_t)KHID * MM;  // second-half rows of W_fc
#pragma unroll
    for (int i = 0; i < 8; ++i) {
        int idx = tid + i * 256;
        int kk = idx >> 5, c = idx & 31;
        Lt[kk][c] = Wg[(size_t)(k0 + kk) * MM + c0 + c];
    }
    __syncthreads();
#pragma unroll
    for (int i = 0; i < 8; ++i) {
        int idx = tid + i * 256;
        int c = idx >> 6, kk = idx & 63;
        WtB[(size_t)(c0 + c) * KHID + k0 + kk] = bf16_rne(Lt[kk][c]);
    }
}

// ---------------------------------------------------------------------------
// K1: T(bf16) = A @ Wg. Persistent: 256 blocks x 256 thr (4 waves), 1 wave/
// SIMD, launch_bounds(256,1) -> 512-VGPR budget (no spill at ~440).
// Wave w owns K-slab [w*256,+256); breg (256 k x 128 cols bf16 = 256 VGPR)
// loaded once via coalesced short8 from WtB[col][k]. aA/aB = 2 chunks of A
// preloaded before the prologue; ping-pong unrolled (max 3 chunks/block).
// Cross-wave K-reduction via 2-slab padded LDS, bf16 uint4 store.
// ---------------------------------------------------------------------------
#define LOAD_A(areg, cc)                                                          \
    {                                                                             \
        const float* Ap_ = A + (size_t)((cc)*16 + r16) * KHID + kbase + g * 8;    \
        _Pragma("unroll") for (int kt = 0; kt < 8; ++kt) {                        \
            areg[2 * kt]     = *(const float4*)(Ap_ + kt * 32);                   \
            areg[2 * kt + 1] = *(const float4*)(Ap_ + kt * 32 + 4);               \
        }                                                                         \
    }

#define PROCESS(areg, cc)                                                         \
    {                                                                             \
        f32x4 acc[8];                                                             \
        _Pragma("unroll") for (int t = 0; t < 8; ++t)                             \
            acc[t] = (f32x4){0.f, 0.f, 0.f, 0.f};                                 \
        _Pragma("unroll") for (int kt = 0; kt < 8; ++kt) {                        \
            short8 af;                                                            \
            unsigned int* au = (unsigned int*)&af;                                \
            au[0] = pk2(areg[2 * kt].x, areg[2 * kt].y);                          \
            au[1] = pk2(areg[2 * kt].z, areg[2 * kt].w);                          \
            au[2] = pk2(areg[2 * kt + 1].x, areg[2 * kt + 1].y);                  \
            au[3] = pk2(areg[2 * kt + 1].z, areg[2 * kt + 1].w);                  \
            _Pragma("unroll") for (int t = 0; t < 8; ++t)                         \
                acc[t] = __builtin_amdgcn_mfma_f32_16x16x32_bf16(                 \
                    af, breg[kt][t], acc[t], 0, 0, 0);                            \
        }                                                                         \
        if ((cc) + 2 * GEMM_GRID < NCHUNK) LOAD_A(areg, (cc) + 2 * GEMM_GRID);    \
        if (w >= 2) {                                                             \
            _Pragma("unroll") for (int t = 0; t < 8; ++t)                         \
                _Pragma("unroll") for (int r = 0; r < 4; ++r)                     \
                    red[w - 2][g * 4 + r][t * 16 + r16] = acc[t][r];              \
        }                                                                         \
        lds_barrier();                                                            \
        if (w < 2) {                                                              \
            _Pragma("unroll") for (int t = 0; t < 8; ++t)                         \
                _Pragma("unroll") for (int r = 0; r < 4; ++r)                     \
                    red[w][g * 4 + r][t * 16 + r16] += acc[t][r];                 \
        }                                                                         \
        lds_barrier();                                                            \
        float4 x0 = *(const float4*)&red[0][orow][c8];                            \
        float4 x1 = *(const float4*)&red[0][orow][c8 + 4];                        \
        float4 y0 = *(const float4*)&red[1][orow][c8];                            \
        float4 y1 = *(const float4*)&red[1][orow][c8 + 4];                        \
        x0.x += y0.x; x0.y += y0.y; x0.z += y0.z; x0.w += y0.w;                   \
        x1.x += y1.x; x1.y += y1.y; x1.z += y1.z; x1.w += y1.w;                   \
        uint4 o;                                                                  \
        o.x = pk2(x0.x, x0.y); o.y = pk2(x0.z, x0.w);                             \
        o.z = pk2(x1.x, x1.y); o.w = pk2(x1.z, x1.w);                             \
        *(uint4*)&T[(size_t)((cc)*16 + orow) * MM + c8] = o;                      \
        lds_barrier();                                                            \
    }

__global__ __launch_bounds__(256, 1) void k_gemm(const float* __restrict__ A,
                                                 const unsigned short* __restrict__ WtB,
                                                 unsigned short* __restrict__ T) {
    const int tid = threadIdx.x;
    const int w = tid >> 6, lane = tid & 63;
    const int r16 = lane & 15, g = lane >> 4;
    const int kbase = w * 256;
    const int orow = tid >> 4, c8 = (tid & 15) * 8;

    const int c0 = blockIdx.x;

    // preload 2 chunks of A (in flight under the B prologue)
    float4 aA[16], aB[16];
    LOAD_A(aA, c0);
    const bool has2 = (c0 + GEMM_GRID) < NCHUNK;
    if (has2) LOAD_A(aB, c0 + GEMM_GRID);

    // B prologue: coalesced short8 loads from bf16 WtB[col][k]
    const unsigned short* Bp = WtB + (size_t)r16 * KHID + kbase + g * 8;
    short8 breg[8][8];
#pragma unroll
    for (int kt = 0; kt < 8; ++kt)
#pragma unroll
        for (int t = 0; t < 8; ++t)
            breg[kt][t] = *(const short8*)(Bp + (size_t)t * 16 * KHID + kt * 32);

    __shared__ float red[2][16][132];

    PROCESS(aA, c0);
    if (has2) {
        PROCESS(aB, c0 + GEMM_GRID);
        if (c0 + 2 * GEMM_GRID < NCHUNK) {
            PROCESS(aA, c0 + 2 * GEMM_GRID);
        }
    }
}

// ---------------------------------------------------------------------------
// K2: partial BN stats over G per (b, chunk of 64 g): grid (16, 32).
// ---------------------------------------------------------------------------
__global__ __launch_bounds__(256) void k_stats(const unsigned short* __restrict__ T,
                                               const int* __restrict__ gPos,
                                               float* __restrict__ ps1,
                                               float* __restrict__ ps2) {
    const int b = blockIdx.y, c = blockIdx.x;
    const int tid = threadIdx.x;

    __shared__ int posl[64];
    __shared__ float r1[4][128], r2[4][128];

    if (tid < 64) posl[tid] = gPos[b * GG + c * 64 + tid];
    __syncthreads();

    const int m = tid & 63, q = tid >> 6;
    float s1a = 0.f, s1b = 0.f, s2a = 0.f, s2b = 0.f;
    for (int g = q; g < 64; g += 4) {
        unsigned int u = *(const unsigned int*)&T[(size_t)posl[g] * MM + m * 2];
        float t0 = bfu((unsigned short)(u & 0xFFFFu));
        float t1 = bfu((unsigned short)(u >> 16));
        s1a += t0; s2a += t0 * t0;
        s1b += t1; s2b += t1 * t1;
    }
    r1[q][m * 2] = s1a; r1[q][m * 2 + 1] = s1b;
    r2[q][m * 2] = s2a; r2[q][m * 2 + 1] = s2b;
    __syncthreads();
    if (tid < 128) {
        ps1[(size_t)(b * 16 + c) * MM + tid] = r1[0][tid] + r1[1][tid] + r1[2][tid] + r1[3][tid];
        ps2[(size_t)(b * 16 + c) * MM + tid] = r2[0][tid] + r2[1][tid] + r2[2][tid] + r2[3][tid];
    }
}

// ---------------------------------------------------------------------------
// K3: final (combine fused): scale/shift from partials, then
// out[b,g] = sigmoid( sum_m relu(scale*T+shift) * W2[m] + b2 ).  grid (16,32)
// ---------------------------------------------------------------------------
__global__ __launch_bounds__(256) void k_final(const unsigned short* __restrict__ T,
                                               const int* __restrict__ gPos,
                                               const float* __restrict__ ps1,
                                               const float* __restrict__ ps2,
                                               const float* __restrict__ gamma,
                                               const float* __restrict__ beta,
                                               const float* __restrict__ W2,
                                               const float* __restrict__ b2,
                                               float* __restrict__ out) {
    const int b = blockIdx.y, gc = blockIdx.x;
    const int tid = threadIdx.x;

    __shared__ float ssc[128], ssh[128];
    __shared__ int posl[64];
    if (tid < 64) posl[tid] = gPos[b * GG + gc * 64 + tid];
    if (tid >= 128 && tid < 256) {
        int mcol = tid - 128;
        float S1 = 0.f, S2 = 0.f;
#pragma unroll
        for (int cc = 0; cc < 16; ++cc) {
            S1 += ps1[(size_t)(b * 16 + cc) * MM + mcol];
            S2 += ps2[(size_t)(b * 16 + cc) * MM + mcol];
        }
        float mean = S1 * (1.f / 1024.f);
        float var  = S2 * (1.f / 1024.f) - mean * mean;
        float rstd = rsqrtf(var + 1e-5f);
        float sc = gamma[mcol] * rstd;
        ssc[mcol] = sc;
        ssh[mcol] = beta[mcol] - sc * mean;
    }
    __syncthreads();

    const int wave = tid >> 6, lane = tid & 63;
    const int m0 = lane * 2, m1 = lane * 2 + 1;
    const float sc0 = ssc[m0], sh0 = ssh[m0], w20 = W2[m0];
    const float sc1 = ssc[m1], sh1 = ssh[m1], w21 = W2[m1];
    const float bias = b2[0];

    for (int i = 0; i < 16; ++i) {
        int gg = wave * 16 + i;
        int pos = posl[gg];
        unsigned int u = *(const unsigned int*)&T[(size_t)pos * MM + m0];
        float t0 = bfu((unsigned short)(u & 0xFFFFu));
        float t1 = bfu((unsigned short)(u >> 16));
        float h0 = fmaxf(sc0 * t0 + sh0, 0.f);
        float h1 = fmaxf(sc1 * t1 + sh1, 0.f);
        float val = h0 * w20 + h1 * w21;
#pragma unroll
        for (int off = 32; off; off >>= 1) val += __shfl_xor(val, off, 64);
        if (lane == 0) out[b * GG + gc * 64 + gg] = 1.f / (1.f + __expf(-(val + bias)));
    }
}

// ---------------------------------------------------------------------------
extern "C" void kernel_launch(void* const* d_in, const int* in_sizes, int n_in,
                              void* d_out, int out_size, void* d_ws, size_t ws_size,
                              hipStream_t stream) {
    const int*   gPos  = (const int*)d_in[3];
    const float* A     = (const float*)d_in[4];
    const float* Wfc   = (const float*)d_in[11];
    const float* gamma = (const float*)d_in[13];
    const float* beta  = (const float*)d_in[14];
    const float* W2    = (const float*)d_in[15];
    const float* b2    = (const float*)d_in[16];
    float* out = (float*)d_out;

    char* ws = (char*)d_ws;
    unsigned short* T   = (unsigned short*)ws;               // 2.56 MB bf16
    unsigned short* WtB = (unsigned short*)(ws + (4 << 20)); // 256 KB bf16
    float* ps1 = (float*)(ws + (8 << 20));                   // 256 KB
    float* ps2 = (float*)(ws + (12 << 20));                  // 256 KB

    hipLaunchKernelGGL(k_convW, dim3(16, 4), dim3(256), 0, stream, Wfc, WtB);
    hipLaunchKernelGGL(k_gemm, dim3(GEMM_GRID), dim3(256), 0, stream, A, WtB, T);
    hipLaunchKernelGGL(k_stats, dim3(16, BB), dim3(256), 0, stream, T, gPos, ps1, ps2);
    hipLaunchKernelGGL(k_final, dim3(16, BB), dim3(256), 0, stream, T, gPos, ps1, ps2,
                       gamma, beta, W2, b2, out);
}